// Round 12
// baseline (1554.687 us; speedup 1.0000x reference)
//
#include <hip/hip_runtime.h>
#include <stdint.h>

#define B_TOTAL 1024
#define T_STEPS 128
#define F_DIM   64
#define H_DIM   256
#define BROWS   16
#define APAD    324   // A_lds row stride in shorts (648 B)
#define NSLOTS  640   // 16 waves * 40 frags; slot = w*40 + kt*4 + j

typedef float f32x4 __attribute__((ext_vector_type(4)));
typedef short bf16x8 __attribute__((ext_vector_type(8)));

__device__ __forceinline__ unsigned short f2bf(float f) {
  unsigned int u = __float_as_uint(f);
  u += 0x7fffu + ((u >> 16) & 1u);
  return (unsigned short)(u >> 16);
}
__device__ __forceinline__ float bf2f(unsigned short b) {
  return __uint_as_float(((unsigned int)b) << 16);
}
__device__ __forceinline__ float sigmoid_f(float x) {
  return 1.0f / (1.0f + __expf(-x));
}
__device__ __forceinline__ float tanh_f(float x) {
  return 1.0f - 2.0f / (1.0f + __expf(2.0f * x));
}

// Pack kernel weights (320x1024 fp32 row-major) into bf16 MFMA-B fragments.
// 16-wave decomposition: slot = w*40 + kt*4 + j; ntile = j*16 + w
// (wave w's 4 ntiles are one 16-col tile per GATE, all at h-cols [16w,16w+16)).
// Wp[(slot*64 + l)*8 + jj] = W[kt*32 + 8*(l>>4) + jj][ntile*16 + (l&15)]
__global__ __launch_bounds__(64) void pack_w_kernel(const float* __restrict__ W,
                                                    unsigned short* __restrict__ Wp) {
  const int slot = blockIdx.x;
  const int w  = slot / 40, r = slot % 40;
  const int kt = r >> 2, j = r & 3;
  const int ntile = j * 16 + w;
  const int l   = threadIdx.x;
  const int col = ntile * 16 + (l & 15);
  const int k0  = kt * 32 + (l >> 4) * 8;
  unsigned short* dst = Wp + ((size_t)slot * 64 + l) * 8;
  #pragma unroll
  for (int jj = 0; jj < 8; ++jj)
    dst[jj] = f2bf(W[(size_t)(k0 + jj) * 1024 + col]);
}

// Opaque pin into the AGPR half of the unified file (gfx950 MFMA reads B
// directly from AGPRs, ISA §10). Un-rematerializable -> stays resident.
// Proven at 96 AGPRs in R10; here 160/wave holds the ENTIRE weight matrix
// on-chip across 16 waves -> zero weight streaming in the scan.
#define PIN_A(x) asm volatile("" : "+a"(x))

#define LD_A(kt) (*(const bf16x8*)&A_lds[cl][(kt) * 32 + kg * 8])

// 64 blocks x 1024 threads (16 waves, 4 waves/SIMD). Weights fully
// register-resident; per step only LDS reads + MFMA + gates + 2 barriers.
__global__ __launch_bounds__(1024, 1) void qlstm_kernel(
    const float* __restrict__ history, const float* __restrict__ head,
    const float* __restrict__ bias,
    const float* __restrict__ w_i, const float* __restrict__ w_f, const float* __restrict__ w_o,
    const unsigned short* __restrict__ Wp,
    const float* __restrict__ fc3_w, const float* __restrict__ fc3_b,
    const float* __restrict__ fc4_w, const float* __restrict__ fc4_b,
    const float* __restrict__ sell_v_w, const float* __restrict__ sell_v_b,
    const float* __restrict__ sell_q_w, const float* __restrict__ sell_q_b,
    const float* __restrict__ buy_v_w, const float* __restrict__ buy_v_b,
    const float* __restrict__ buy_q_w, const float* __restrict__ buy_q_b,
    float* __restrict__ out) {

  __shared__ unsigned short A_lds[BROWS][APAD];  // bf16: [r][k], k<64 = x_t, 64..319 = h_t
  __shared__ float feat[BROWS][258];
  __shared__ float v_l[BROWS][128];
  __shared__ float q_l[BROWS][128];
  __shared__ float ispos[BROWS];

  const int tid = threadIdx.x;
  const int w   = tid >> 6;       // wave 0..15
  const int l   = tid & 63;
  const int cl  = l & 15;         // A-row index within tile / acc col
  const int kg  = l >> 4;         // 0..3
  const int rb  = blockIdx.x * BROWS;
  const int xr  = tid >> 6;       // x-staging row 0..15
  const int xc  = tid & 63;       // x-staging col 0..63

  // ---- weights: fully register-resident, 40 frags = 160 AGPRs/wave ----
  const unsigned short* wp_wl = Wp + (size_t)(w * 40) * 512 + l * 8;
  bf16x8 wreg[10][4];
  #pragma unroll
  for (int kt = 0; kt < 10; ++kt)
    #pragma unroll
    for (int j = 0; j < 4; ++j) {
      wreg[kt][j] = *(const bf16x8*)(wp_wl + (kt * 4 + j) * 512);
      PIN_A(wreg[kt][j]);
    }

  // ---- zero A (h_0 = 0), stage x_0: one float per thread ----
  for (int i = tid; i < BROWS * APAD; i += 1024)
    ((unsigned short*)A_lds)[i] = 0;
  __syncthreads();
  A_lds[xr][xc] = f2bf(history[((size_t)(rb + xr) * T_STEPS + 0) * F_DIM + xc]);

  // ---- per-lane gate constants: lane owns h-col hc = w*16+cl, rows 4kg+q ----
  const int hc = w * 16 + cl;
  const float wi_r = w_i[hc], wf_r = w_f[hc], wo_r = w_o[hc];
  float bias_r[4];
  #pragma unroll
  for (int j = 0; j < 4; ++j) bias_r[j] = bias[j * 256 + hc];

  float c_st[4] = {0.f, 0.f, 0.f, 0.f};
  __syncthreads();

  // ---- the scan: no weight traffic, just LDS -> MFMA -> gates ----
  for (int t = 0; t < T_STEPS; ++t) {
    const bool havex = (t + 1 < T_STEPS);
    float xv = 0.0f;
    if (havex)
      xv = history[((size_t)(rb + xr) * T_STEPS + (t + 1)) * F_DIM + xc];

    f32x4 acc[4];
    #pragma unroll
    for (int j = 0; j < 4; ++j) acc[j] = (f32x4){0.f, 0.f, 0.f, 0.f};

    #pragma unroll
    for (int kt = 0; kt < 10; ++kt) {
      const bf16x8 af = LD_A(kt);
      #pragma unroll
      for (int j = 0; j < 4; ++j)
        acc[j] = __builtin_amdgcn_mfma_f32_16x16x32_bf16(af, wreg[kt][j], acc[j], 0, 0, 0);
    }

    // gates: acc[j][q] = z[row 4kg+q][col j*256 + hc]; j indexes gate i,j,f,o
    float h_val[4];
    #pragma unroll
    for (int q = 0; q < 4; ++q) {
      const float c_old = c_st[q];
      const float ig = sigmoid_f(acc[0][q] + bias_r[0] + wi_r * c_old);
      const float fg = sigmoid_f(acc[2][q] + bias_r[2] + 1.0f + wf_r * c_old);
      const float jg = tanh_f(acc[1][q] + bias_r[1]);
      const float c_new = fg * c_old + ig * jg;
      const float og = sigmoid_f(acc[3][q] + bias_r[3] + wo_r * c_new);
      c_st[q] = c_new;
      h_val[q] = og * tanh_f(c_new);
    }

    __syncthreads();  // all A_lds reads for step t done (all 16 waves)

    #pragma unroll
    for (int q = 0; q < 4; ++q)
      A_lds[4 * kg + q][64 + hc] = f2bf(h_val[q]);   // 16 waves cover all 256 cols
    if (havex)
      A_lds[xr][xc] = f2bf(xv);
    __syncthreads();  // h_{t+1}, x_{t+1} assembled
  }

  // ---- epilogue (1024 threads) ----
  for (int i = tid; i < BROWS * H_DIM; i += 1024) {
    const int r = i >> 8, hcc = i & 255;
    feat[r][2 + hcc] = bf2f(A_lds[r][64 + hcc]);
  }
  if (tid < BROWS) {
    feat[tid][0] = head[(rb + tid) * 3 + 1];
    feat[tid][1] = head[(rb + tid) * 3 + 2];
    ispos[tid] = head[(rb + tid) * 3 + 0];
  }
  __syncthreads();

  #pragma unroll
  for (int p = 0; p < 2; ++p) {
    const int idx = p * 1024 + tid;
    const int r = idx >> 7, hh = idx & 127;
    float s3 = fc3_b[hh], s4 = fc4_b[hh];
    for (int k = 0; k < 258; ++k) {
      const float fv = feat[r][k];
      s3 += fv * fc3_w[k * 128 + hh];
      s4 += fv * fc4_w[k * 128 + hh];
    }
    v_l[r][hh] = fmaxf(s3, 0.0f);
    q_l[r][hh] = fmaxf(s4, 0.0f);
  }
  __syncthreads();

  if (tid < BROWS) {
    const int r = tid;
    float pa0 = sell_q_b[0], pa1 = sell_q_b[1];
    float ea0 = buy_q_b[0],  ea1 = buy_q_b[1];
    float sv = sell_v_b[0], bv = buy_v_b[0];
    for (int hh = 0; hh < 128; ++hh) {
      const float qv = q_l[r][hh], vv = v_l[r][hh];
      pa0 += qv * sell_q_w[hh * 2 + 0];
      pa1 += qv * sell_q_w[hh * 2 + 1];
      ea0 += qv * buy_q_w[hh * 2 + 0];
      ea1 += qv * buy_q_w[hh * 2 + 1];
      sv += vv * sell_v_w[hh];
      bv += vv * buy_v_w[hh];
    }
    const float pm = 0.5f * (pa0 + pa1), em = 0.5f * (ea0 + ea1);
    const float pq0 = pa0 - pm + sv, pq1 = pa1 - pm + sv;
    const float eq0 = ea0 - em + bv, eq1 = ea1 - em + bv;
    const float ip = ispos[r];
    out[(size_t)(rb + r) * 2 + 0] = (ip != 0.0f) ? pq0 : eq0;
    out[(size_t)(rb + r) * 2 + 1] = ((1.0f - ip) != 0.0f) ? pq1 : eq1;
  }
}

extern "C" void kernel_launch(void* const* d_in, const int* in_sizes, int n_in,
                              void* d_out, int out_size, void* d_ws, size_t ws_size,
                              hipStream_t stream) {
  (void)in_sizes; (void)n_in; (void)out_size; (void)ws_size;
  const float* history  = (const float*)d_in[0];
  const float* head     = (const float*)d_in[1];
  const float* Wk       = (const float*)d_in[2];
  const float* bias     = (const float*)d_in[3];
  const float* w_i      = (const float*)d_in[4];
  const float* w_f      = (const float*)d_in[5];
  const float* w_o      = (const float*)d_in[6];
  const float* fc3_w    = (const float*)d_in[7];
  const float* fc3_b    = (const float*)d_in[8];
  const float* fc4_w    = (const float*)d_in[9];
  const float* fc4_b    = (const float*)d_in[10];
  const float* sell_v_w = (const float*)d_in[11];
  const float* sell_v_b = (const float*)d_in[12];
  const float* sell_q_w = (const float*)d_in[13];
  const float* sell_q_b = (const float*)d_in[14];
  const float* buy_v_w  = (const float*)d_in[15];
  const float* buy_v_b  = (const float*)d_in[16];
  const float* buy_q_w  = (const float*)d_in[17];
  const float* buy_q_b  = (const float*)d_in[18];

  unsigned short* Wp = (unsigned short*)d_ws;  // 640 slots * 1 KiB = 640 KiB

  pack_w_kernel<<<NSLOTS, 64, 0, stream>>>(Wk, Wp);
  qlstm_kernel<<<B_TOTAL / BROWS, 1024, 0, stream>>>(
      history, head, bias, w_i, w_f, w_o, Wp,
      fc3_w, fc3_b, fc4_w, fc4_b,
      sell_v_w, sell_v_b, sell_q_w, sell_q_b,
      buy_v_w, buy_v_b, buy_q_w, buy_q_b,
      (float*)d_out);
}

// Round 13
// 813.724 us; speedup vs baseline: 1.9106x; 1.9106x over previous
//
#include <hip/hip_runtime.h>
#include <stdint.h>

#define B_TOTAL 1024
#define T_STEPS 128
#define F_DIM   64
#define H_DIM   256
#define BROWS   16
#define APAD    324   // row stride 648B
#define NSLOTS  640   // 8 waves * 80 frags; slot = w*80 + kt*8 + ct*4 + g

typedef float f32x4 __attribute__((ext_vector_type(4)));
typedef short bf16x8 __attribute__((ext_vector_type(8)));

__device__ __forceinline__ unsigned short f2bf(float f) {
  unsigned int u = __float_as_uint(f);
  u += 0x7fffu + ((u >> 16) & 1u);
  return (unsigned short)(u >> 16);
}
__device__ __forceinline__ float bf2f(unsigned short b) {
  return __uint_as_float(((unsigned int)b) << 16);
}
__device__ __forceinline__ float sigmoid_f(float x) {
  return 1.0f / (1.0f + __expf(-x));
}
__device__ __forceinline__ float tanh_f(float x) {
  return 1.0f - 2.0f / (1.0f + __expf(2.0f * x));
}

// Pack kernel weights (320x1024 fp32 row-major) into bf16 MFMA-B fragments,
// wave-major: slot = w*80 + kt*8 + ct*4 + g; ntile = g*16 + w*2 + ct.
__global__ __launch_bounds__(64) void pack_w_kernel(const float* __restrict__ W,
                                                    unsigned short* __restrict__ Wp) {
  const int slot = blockIdx.x;
  const int w  = slot / 80, r = slot % 80;
  const int kt = r >> 3, ct = (r >> 2) & 1, g = r & 3;
  const int ntile = g * 16 + w * 2 + ct;
  const int l   = threadIdx.x;
  const int col = ntile * 16 + (l & 15);
  const int k0  = kt * 32 + (l >> 4) * 8;
  unsigned short* dst = Wp + ((size_t)slot * 64 + l) * 8;
  #pragma unroll
  for (int j = 0; j < 8; ++j)
    dst[j] = f2bf(W[(size_t)(k0 + j) * 1024 + col]);
}

// Opaque pin into the AGPR half of the unified file (gfx950 MFMA reads B
// directly from AGPRs, ISA §10). Un-rematerializable -> stays resident.
// ALL 4 resident kt go to AGPR (128 + 32 acc = 160 AGPR; arch-VGPR demand
// stays ~100 < the 128 grant -> no spill, unlike R10/R11's kt3-VGPR tier).
#define PIN_A(x) asm volatile("" : "+a"(x))

// Issue 4 streamed fragments of (kt,ct). Wp is shorts; frag slot = 512 shorts.
// Buffers live ONLY within one loop iteration (no loop-carried async regs).
#define ISSUE_BATCH(buf, kt, ct) do {                                        \
    const unsigned short* _p = wp_wl + ((kt) * 8 + (ct) * 4) * 512;          \
    asm volatile("global_load_dwordx4 %0, %4, off\n\t"                       \
                 "global_load_dwordx4 %1, %4, off offset:1024\n\t"           \
                 "global_load_dwordx4 %2, %4, off offset:2048\n\t"           \
                 "global_load_dwordx4 %3, %4, off offset:3072"               \
                 : "=&v"(buf[0]), "=&v"(buf[1]), "=&v"(buf[2]), "=&v"(buf[3])\
                 : "v"(_p));                                                 \
  } while (0)

// Counted wait + sched fences (rule #18), 4 MFMAs into acc[ct].
#define CONSUME_S(buf, ct, afv, N) do {                                      \
    asm volatile("s_waitcnt vmcnt(" #N ")" ::: "memory");                    \
    __builtin_amdgcn_sched_barrier(0);                                       \
    acc[ct][0] = __builtin_amdgcn_mfma_f32_16x16x32_bf16(afv, buf[0], acc[ct][0], 0, 0, 0); \
    acc[ct][1] = __builtin_amdgcn_mfma_f32_16x16x32_bf16(afv, buf[1], acc[ct][1], 0, 0, 0); \
    acc[ct][2] = __builtin_amdgcn_mfma_f32_16x16x32_bf16(afv, buf[2], acc[ct][2], 0, 0, 0); \
    acc[ct][3] = __builtin_amdgcn_mfma_f32_16x16x32_bf16(afv, buf[3], acc[ct][3], 0, 0, 0); \
    __builtin_amdgcn_sched_barrier(0);                                       \
  } while (0)

#define LD_A(kt) (*(const bf16x8*)&A_lds[cl][(kt) * 32 + kg * 8])

__global__ __launch_bounds__(512, 1) void qlstm_kernel(
    const float* __restrict__ history, const float* __restrict__ head,
    const float* __restrict__ bias,
    const float* __restrict__ w_i, const float* __restrict__ w_f, const float* __restrict__ w_o,
    const unsigned short* __restrict__ Wp,
    const float* __restrict__ fc3_w, const float* __restrict__ fc3_b,
    const float* __restrict__ fc4_w, const float* __restrict__ fc4_b,
    const float* __restrict__ sell_v_w, const float* __restrict__ sell_v_b,
    const float* __restrict__ sell_q_w, const float* __restrict__ sell_q_b,
    const float* __restrict__ buy_v_w, const float* __restrict__ buy_v_b,
    const float* __restrict__ buy_q_w, const float* __restrict__ buy_q_b,
    float* __restrict__ out) {

  __shared__ unsigned short A_lds[BROWS][APAD];   // bf16: [r][k], k<64 = x_t, 64..319 = h
  __shared__ unsigned short W_lds[128 * 512];     // 128 KiB: kt4,5; s = w*16 + (kt-4)*8 + ct*4 + g

  const int tid = threadIdx.x;
  const int w   = tid >> 6;       // wave 0..7
  const int l   = tid & 63;
  const int cl  = l & 15;         // A-row / acc-col
  const int kg  = l >> 4;         // 0..3
  const int rb  = blockIdx.x * BROWS;

  const unsigned short* wp_wl = Wp + (size_t)(w * 80) * 512 + l * 8;
  const unsigned short* wl_l  = W_lds + (w * 16) * 512 + l * 8;

  // ---- preload LDS weight tier: frags f=32..47 (kt4,5) per wave ----
  for (int i = tid; i < 128 * 64; i += 512) {
    const int s = i >> 6, l2 = i & 63;
    const int fsrc = (s >> 4) * 80 + 32 + (s & 15);   // kt in {4,5}
    *(uint4*)&W_lds[((size_t)s * 64 + l2) * 8] =
        *(const uint4*)&Wp[((size_t)fsrc * 64 + l2) * 8];
  }

  // ---- register tier: kt 0..3 (32 frags = 128 regs), ALL AGPR-pinned ----
  bf16x8 wreg[4][2][4];
  #pragma unroll
  for (int kt = 0; kt < 4; ++kt)
    #pragma unroll
    for (int ct = 0; ct < 2; ++ct)
      #pragma unroll
      for (int g = 0; g < 4; ++g) {
        wreg[kt][ct][g] = *(const bf16x8*)(wp_wl + (kt * 8 + ct * 4 + g) * 512);
        PIN_A(wreg[kt][ct][g]);
      }

  // ---- zero A, stage x_0 ----
  for (int i = tid; i < BROWS * APAD; i += 512)
    ((unsigned short*)A_lds)[i] = 0;
  __syncthreads();
  {
    const int r  = tid >> 5;
    const int f0 = (tid & 31) * 2;
    const float2 xv0 = *(const float2*)&history[((size_t)(rb + r) * T_STEPS + 0) * F_DIM + f0];
    *(unsigned int*)&A_lds[r][f0] =
        (unsigned int)f2bf(xv0.x) | ((unsigned int)f2bf(xv0.y) << 16);
  }

  // ---- per-lane gate constants ----
  float bias_r[2][4], wi_r[2], wf_r[2], wo_r[2];
  #pragma unroll
  for (int ct = 0; ct < 2; ++ct) {
    const int hc = (w * 2 + ct) * 16 + cl;
    wi_r[ct] = w_i[hc]; wf_r[ct] = w_f[hc]; wo_r[ct] = w_o[hc];
    #pragma unroll
    for (int g = 0; g < 4; ++g) bias_r[ct][g] = bias[g * 256 + hc];
  }

  float c_st[2][4];
  #pragma unroll
  for (int ct = 0; ct < 2; ++ct)
    #pragma unroll
    for (int q = 0; q < 4; ++q) c_st[ct][q] = 0.0f;

  __syncthreads();

  // ---- the scan. Stream state iteration-local; 3-buffer vmcnt(8) ladder
  //      (R7's proven high-MLP shape, applied to 8 batches = kt6..9). ----
  for (int t = 0; t < T_STEPS; ++t) {
    // x prefetch for t+1: issued FIRST -> oldest in vmcnt queue, retired by
    // the first vmcnt(8) below.
    float2 xv;
    const bool havex = (t + 1 < T_STEPS);
    if (havex) {
      const float* xp =
          &history[((size_t)(rb + (tid >> 5)) * T_STEPS + (t + 1)) * F_DIM + (tid & 31) * 2];
      asm volatile("global_load_dwordx2 %0, %1, off" : "=&v"(xv) : "v"(xp));
    }

    f32x4 acc[2][4];
    #pragma unroll
    for (int ct = 0; ct < 2; ++ct)
      #pragma unroll
      for (int g = 0; g < 4; ++g)
        acc[ct][g] = (f32x4){0.f, 0.f, 0.f, 0.f};

    // stream tier = kt6..9 (8 batches), 3 buffers, high MLP
    bf16x8 sA[4], sB[4], sC[4];
    ISSUE_BATCH(sA, 6, 0);
    ISSUE_BATCH(sB, 6, 1);
    ISSUE_BATCH(sC, 7, 0);

    // reg tier kt0..3 (32 MFMAs cover L2 latency of the first batches)
    #pragma unroll
    for (int kt = 0; kt < 4; ++kt) {
      const bf16x8 afr = LD_A(kt);
      #pragma unroll
      for (int ct = 0; ct < 2; ++ct)
        #pragma unroll
        for (int g = 0; g < 4; ++g)
          acc[ct][g] =
              __builtin_amdgcn_mfma_f32_16x16x32_bf16(afr, wreg[kt][ct][g], acc[ct][g], 0, 0, 0);
    }

    // LDS tier kt4..5 (LDS pipe, parallel to the stream)
    #pragma unroll
    for (int kt = 4; kt < 6; ++kt) {
      const bf16x8 afr = LD_A(kt);
      #pragma unroll
      for (int ct = 0; ct < 2; ++ct)
        #pragma unroll
        for (int g = 0; g < 4; ++g) {
          const bf16x8 b = *(const bf16x8*)(wl_l + ((kt - 4) * 8 + ct * 4 + g) * 512);
          acc[ct][g] = __builtin_amdgcn_mfma_f32_16x16x32_bf16(afr, b, acc[ct][g], 0, 0, 0);
        }
    }

    // ladder (hand-traced): queue 13 (x+12) -> vmcnt(8) keeps 8+ in flight;
    // every ISSUE strictly follows its buffer's consume; drains to 0.
    bf16x8 af;
    af = LD_A(6);
    CONSUME_S(sA, 0, af, 8); ISSUE_BATCH(sA, 7, 1);
    CONSUME_S(sB, 1, af, 8); ISSUE_BATCH(sB, 8, 0);
    af = LD_A(7);
    CONSUME_S(sC, 0, af, 8); ISSUE_BATCH(sC, 8, 1);
    CONSUME_S(sA, 1, af, 8); ISSUE_BATCH(sA, 9, 0);
    af = LD_A(8);
    CONSUME_S(sB, 0, af, 8); ISSUE_BATCH(sB, 9, 1);
    CONSUME_S(sC, 1, af, 8);
    af = LD_A(9);
    CONSUME_S(sA, 0, af, 4);
    CONSUME_S(sB, 1, af, 0);
    // queue EMPTY: nothing outstanding crosses the barrier.

    // gates + state update (z order: i, j, f, o)
    float h_val[2][4];
    #pragma unroll
    for (int ct = 0; ct < 2; ++ct) {
      #pragma unroll
      for (int q = 0; q < 4; ++q) {
        const float c_old = c_st[ct][q];
        const float ig = sigmoid_f(acc[ct][0][q] + bias_r[ct][0] + wi_r[ct] * c_old);
        const float fg = sigmoid_f(acc[ct][2][q] + bias_r[ct][2] + 1.0f + wf_r[ct] * c_old);
        const float jg = tanh_f(acc[ct][1][q] + bias_r[ct][1]);
        const float c_new = fg * c_old + ig * jg;
        const float og = sigmoid_f(acc[ct][3][q] + bias_r[ct][3] + wo_r[ct] * c_new);
        c_st[ct][q] = c_new;
        h_val[ct][q] = og * tanh_f(c_new);
      }
    }

    __syncthreads();  // all A_lds reads for step t done

    #pragma unroll
    for (int ct = 0; ct < 2; ++ct) {
      const int hc = (w * 2 + ct) * 16 + cl;
      #pragma unroll
      for (int q = 0; q < 4; ++q)
        A_lds[4 * kg + q][64 + hc] = f2bf(h_val[ct][q]);
    }
    if (havex) {
      const int r  = tid >> 5;
      const int f0 = (tid & 31) * 2;
      *(unsigned int*)&A_lds[r][f0] =
          (unsigned int)f2bf(xv.x) | ((unsigned int)f2bf(xv.y) << 16);
    }
    __syncthreads();
  }

  // safety drain before LDS overlay reuse
  asm volatile("s_waitcnt vmcnt(0)" ::: "memory");
  __builtin_amdgcn_sched_barrier(0);
  __syncthreads();

  // ---- epilogue: overlay scratch onto W_lds (all weight reads done) ----
  float* feat  = (float*)W_lds;            // [16][258]
  float* v_l   = feat + BROWS * 258;       // [16][128]
  float* q_l   = v_l + BROWS * 128;        // [16][128]
  float* ispos = q_l + BROWS * 128;        // [16]

  for (int i = tid; i < BROWS * H_DIM; i += 512) {
    const int r = i >> 8, hc = i & 255;
    feat[r * 258 + 2 + hc] = bf2f(A_lds[r][64 + hc]);
  }
  if (tid < BROWS) {
    feat[tid * 258 + 0] = head[(rb + tid) * 3 + 1];
    feat[tid * 258 + 1] = head[(rb + tid) * 3 + 2];
    ispos[tid] = head[(rb + tid) * 3 + 0];
  }
  __syncthreads();

  #pragma unroll
  for (int p = 0; p < 4; ++p) {
    const int idx = p * 512 + tid;
    const int r = idx >> 7, hh = idx & 127;
    float s3 = fc3_b[hh], s4 = fc4_b[hh];
    for (int k = 0; k < 258; ++k) {
      const float fv = feat[r * 258 + k];
      s3 += fv * fc3_w[k * 128 + hh];
      s4 += fv * fc4_w[k * 128 + hh];
    }
    v_l[r * 128 + hh] = fmaxf(s3, 0.0f);
    q_l[r * 128 + hh] = fmaxf(s4, 0.0f);
  }
  __syncthreads();

  if (tid < BROWS) {
    const int r = tid;
    float pa0 = sell_q_b[0], pa1 = sell_q_b[1];
    float ea0 = buy_q_b[0],  ea1 = buy_q_b[1];
    float sv = sell_v_b[0], bv = buy_v_b[0];
    for (int hh = 0; hh < 128; ++hh) {
      const float qv = q_l[r * 128 + hh], vv = v_l[r * 128 + hh];
      pa0 += qv * sell_q_w[hh * 2 + 0];
      pa1 += qv * sell_q_w[hh * 2 + 1];
      ea0 += qv * buy_q_w[hh * 2 + 0];
      ea1 += qv * buy_q_w[hh * 2 + 1];
      sv += vv * sell_v_w[hh];
      bv += vv * buy_v_w[hh];
    }
    const float pm = 0.5f * (pa0 + pa1), em = 0.5f * (ea0 + ea1);
    const float pq0 = pa0 - pm + sv, pq1 = pa1 - pm + sv;
    const float eq0 = ea0 - em + bv, eq1 = ea1 - em + bv;
    const float ip = ispos[r];
    out[(size_t)(rb + r) * 2 + 0] = (ip != 0.0f) ? pq0 : eq0;
    out[(size_t)(rb + r) * 2 + 1] = ((1.0f - ip) != 0.0f) ? pq1 : eq1;
  }
}

extern "C" void kernel_launch(void* const* d_in, const int* in_sizes, int n_in,
                              void* d_out, int out_size, void* d_ws, size_t ws_size,
                              hipStream_t stream) {
  (void)in_sizes; (void)n_in; (void)out_size; (void)ws_size;
  const float* history  = (const float*)d_in[0];
  const float* head     = (const float*)d_in[1];
  const float* Wk       = (const float*)d_in[2];
  const float* bias     = (const float*)d_in[3];
  const float* w_i      = (const float*)d_in[4];
  const float* w_f      = (const float*)d_in[5];
  const float* w_o      = (const float*)d_in[6];
  const float* fc3_w    = (const float*)d_in[7];
  const float* fc3_b    = (const float*)d_in[8];
  const float* fc4_w    = (const float*)d_in[9];
  const float* fc4_b    = (const float*)d_in[10];
  const float* sell_v_w = (const float*)d_in[11];
  const float* sell_v_b = (const float*)d_in[12];
  const float* sell_q_w = (const float*)d_in[13];
  const float* sell_q_b = (const float*)d_in[14];
  const float* buy_v_w  = (const float*)d_in[15];
  const float* buy_v_b  = (const float*)d_in[16];
  const float* buy_q_w  = (const float*)d_in[17];
  const float* buy_q_b  = (const float*)d_in[18];

  unsigned short* Wp = (unsigned short*)d_ws;  // 640 slots * 1 KiB = 640 KiB

  pack_w_kernel<<<NSLOTS, 64, 0, stream>>>(Wk, Wp);
  qlstm_kernel<<<B_TOTAL / BROWS, 512, 0, stream>>>(
      history, head, bias, w_i, w_f, w_o, Wp,
      fc3_w, fc3_b, fc4_w, fc4_b,
      sell_v_w, sell_v_b, sell_q_w, sell_q_b,
      buy_v_w, buy_v_b, buy_q_w, buy_q_b,
      (float*)d_out);
}

// Round 14
// 755.305 us; speedup vs baseline: 2.0584x; 1.0773x over previous
//
#include <hip/hip_runtime.h>
#include <stdint.h>

#define B_TOTAL 1024
#define T_STEPS 128
#define F_DIM   64
#define H_DIM   256
#define BROWS   16
#define APAD    324   // row stride 648B
#define NSLOTS  640   // 8 waves * 80 frags; slot = w*80 + kt*8 + ct*4 + g

typedef float f32x4 __attribute__((ext_vector_type(4)));
typedef short bf16x8 __attribute__((ext_vector_type(8)));

__device__ __forceinline__ unsigned short f2bf(float f) {
  unsigned int u = __float_as_uint(f);
  u += 0x7fffu + ((u >> 16) & 1u);
  return (unsigned short)(u >> 16);
}
__device__ __forceinline__ float bf2f(unsigned short b) {
  return __uint_as_float(((unsigned int)b) << 16);
}
__device__ __forceinline__ float sigmoid_f(float x) {
  return 1.0f / (1.0f + __expf(-x));
}
__device__ __forceinline__ float tanh_f(float x) {
  return 1.0f - 2.0f / (1.0f + __expf(2.0f * x));
}

// Pack kernel weights (320x1024 fp32 row-major) into bf16 MFMA-B fragments,
// wave-major: slot = w*80 + kt*8 + ct*4 + g; ntile = g*16 + w*2 + ct.
__global__ __launch_bounds__(64) void pack_w_kernel(const float* __restrict__ W,
                                                    unsigned short* __restrict__ Wp) {
  const int slot = blockIdx.x;
  const int w  = slot / 80, r = slot % 80;
  const int kt = r >> 3, ct = (r >> 2) & 1, g = r & 3;
  const int ntile = g * 16 + w * 2 + ct;
  const int l   = threadIdx.x;
  const int col = ntile * 16 + (l & 15);
  const int k0  = kt * 32 + (l >> 4) * 8;
  unsigned short* dst = Wp + ((size_t)slot * 64 + l) * 8;
  #pragma unroll
  for (int j = 0; j < 8; ++j)
    dst[j] = f2bf(W[(size_t)(k0 + j) * 1024 + col]);
}

// Opaque pin: un-rematerializable VGPR def -> stays resident. Plain "+v" is
// the ONLY pin class that has produced no-spill kernels (R3/R7); "+a" pins
// spilled every time (R10/R11/R13 — v<->a copy shadows inflate demand).
#define PIN_V(x) asm volatile("" : "+v"(x))

// Issue 4 streamed fragments of (kt,ct). Wp is shorts; frag slot = 512 shorts.
// Buffers live ONLY within one loop iteration (no loop-carried async regs).
#define ISSUE_BATCH(buf, kt, ct) do {                                        \
    const unsigned short* _p = wp_wl + ((kt) * 8 + (ct) * 4) * 512;          \
    asm volatile("global_load_dwordx4 %0, %4, off\n\t"                       \
                 "global_load_dwordx4 %1, %4, off offset:1024\n\t"           \
                 "global_load_dwordx4 %2, %4, off offset:2048\n\t"           \
                 "global_load_dwordx4 %3, %4, off offset:3072"               \
                 : "=&v"(buf[0]), "=&v"(buf[1]), "=&v"(buf[2]), "=&v"(buf[3])\
                 : "v"(_p));                                                 \
  } while (0)

// Counted wait + sched fences (rule #18), 4 MFMAs into acc[ct].
#define CONSUME_S(buf, ct, afv, N) do {                                      \
    asm volatile("s_waitcnt vmcnt(" #N ")" ::: "memory");                    \
    __builtin_amdgcn_sched_barrier(0);                                       \
    acc[ct][0] = __builtin_amdgcn_mfma_f32_16x16x32_bf16(afv, buf[0], acc[ct][0], 0, 0, 0); \
    acc[ct][1] = __builtin_amdgcn_mfma_f32_16x16x32_bf16(afv, buf[1], acc[ct][1], 0, 0, 0); \
    acc[ct][2] = __builtin_amdgcn_mfma_f32_16x16x32_bf16(afv, buf[2], acc[ct][2], 0, 0, 0); \
    acc[ct][3] = __builtin_amdgcn_mfma_f32_16x16x32_bf16(afv, buf[3], acc[ct][3], 0, 0, 0); \
    __builtin_amdgcn_sched_barrier(0);                                       \
  } while (0)

#define LD_A(kt) (*(const bf16x8*)&A_lds[cl][(kt) * 32 + kg * 8])

__global__ __launch_bounds__(512, 1) void qlstm_kernel(
    const float* __restrict__ history, const float* __restrict__ head,
    const float* __restrict__ bias,
    const float* __restrict__ w_i, const float* __restrict__ w_f, const float* __restrict__ w_o,
    const unsigned short* __restrict__ Wp,
    const float* __restrict__ fc3_w, const float* __restrict__ fc3_b,
    const float* __restrict__ fc4_w, const float* __restrict__ fc4_b,
    const float* __restrict__ sell_v_w, const float* __restrict__ sell_v_b,
    const float* __restrict__ sell_q_w, const float* __restrict__ sell_q_b,
    const float* __restrict__ buy_v_w, const float* __restrict__ buy_v_b,
    const float* __restrict__ buy_q_w, const float* __restrict__ buy_q_b,
    float* __restrict__ out) {

  __shared__ unsigned short A_lds[BROWS][APAD];   // bf16: [r][k], k<64 = x_t, 64..319 = h
  __shared__ unsigned short W_lds[128 * 512];     // 128 KiB: kt4,5; s = w*16 + (kt-4)*8 + ct*4 + g

  const int tid = threadIdx.x;
  const int w   = tid >> 6;       // wave 0..7
  const int l   = tid & 63;
  const int cl  = l & 15;         // A-row / acc-col
  const int kg  = l >> 4;         // 0..3
  const int rb  = blockIdx.x * BROWS;

  const unsigned short* wp_wl = Wp + (size_t)(w * 80) * 512 + l * 8;
  const unsigned short* wl_l  = W_lds + (w * 16) * 512 + l * 8;

  // ---- preload LDS weight tier: frags f=32..47 (kt4,5) per wave ----
  for (int i = tid; i < 128 * 64; i += 512) {
    const int s = i >> 6, l2 = i & 63;
    const int fsrc = (s >> 4) * 80 + 32 + (s & 15);   // kt in {4,5}
    *(uint4*)&W_lds[((size_t)s * 64 + l2) * 8] =
        *(const uint4*)&Wp[((size_t)fsrc * 64 + l2) * 8];
  }

  // ---- register tier: kt 0..3 (32 frags = 128 regs), VGPR-pinned ----
  bf16x8 wreg[4][2][4];
  #pragma unroll
  for (int kt = 0; kt < 4; ++kt)
    #pragma unroll
    for (int ct = 0; ct < 2; ++ct)
      #pragma unroll
      for (int g = 0; g < 4; ++g) {
        wreg[kt][ct][g] = *(const bf16x8*)(wp_wl + (kt * 8 + ct * 4 + g) * 512);
        PIN_V(wreg[kt][ct][g]);
      }

  // ---- zero A, stage x_0 ----
  for (int i = tid; i < BROWS * APAD; i += 512)
    ((unsigned short*)A_lds)[i] = 0;
  __syncthreads();
  {
    const int r  = tid >> 5;
    const int f0 = (tid & 31) * 2;
    const float2 xv0 = *(const float2*)&history[((size_t)(rb + r) * T_STEPS + 0) * F_DIM + f0];
    *(unsigned int*)&A_lds[r][f0] =
        (unsigned int)f2bf(xv0.x) | ((unsigned int)f2bf(xv0.y) << 16);
  }

  // ---- per-lane gate constants ----
  float bias_r[2][4], wi_r[2], wf_r[2], wo_r[2];
  #pragma unroll
  for (int ct = 0; ct < 2; ++ct) {
    const int hc = (w * 2 + ct) * 16 + cl;
    wi_r[ct] = w_i[hc]; wf_r[ct] = w_f[hc]; wo_r[ct] = w_o[hc];
    #pragma unroll
    for (int g = 0; g < 4; ++g) bias_r[ct][g] = bias[g * 256 + hc];
  }

  float c_st[2][4];
  #pragma unroll
  for (int ct = 0; ct < 2; ++ct)
    #pragma unroll
    for (int q = 0; q < 4; ++q) c_st[ct][q] = 0.0f;

  __syncthreads();

  // ---- the scan. Stream state iteration-local; 3-buffer vmcnt(8) ladder
  //      (R7's proven high-MLP shape) over the 8 batches of kt6..9. ----
  for (int t = 0; t < T_STEPS; ++t) {
    // x prefetch for t+1: issued FIRST -> oldest in vmcnt queue, retired by
    // the first vmcnt(8) below.
    float2 xv;
    const bool havex = (t + 1 < T_STEPS);
    if (havex) {
      const float* xp =
          &history[((size_t)(rb + (tid >> 5)) * T_STEPS + (t + 1)) * F_DIM + (tid & 31) * 2];
      asm volatile("global_load_dwordx2 %0, %1, off" : "=&v"(xv) : "v"(xp));
    }

    f32x4 acc[2][4];
    #pragma unroll
    for (int ct = 0; ct < 2; ++ct)
      #pragma unroll
      for (int g = 0; g < 4; ++g)
        acc[ct][g] = (f32x4){0.f, 0.f, 0.f, 0.f};

    // stream tier = kt6..9 (8 batches), 3 buffers, high MLP
    bf16x8 sA[4], sB[4], sC[4];
    ISSUE_BATCH(sA, 6, 0);
    ISSUE_BATCH(sB, 6, 1);
    ISSUE_BATCH(sC, 7, 0);

    // reg tier kt0..3 (32 MFMAs cover L2 latency of the first batches)
    #pragma unroll
    for (int kt = 0; kt < 4; ++kt) {
      const bf16x8 afr = LD_A(kt);
      #pragma unroll
      for (int ct = 0; ct < 2; ++ct)
        #pragma unroll
        for (int g = 0; g < 4; ++g)
          acc[ct][g] =
              __builtin_amdgcn_mfma_f32_16x16x32_bf16(afr, wreg[kt][ct][g], acc[ct][g], 0, 0, 0);
    }

    // LDS tier kt4..5 (LDS pipe, parallel to the stream)
    #pragma unroll
    for (int kt = 4; kt < 6; ++kt) {
      const bf16x8 afr = LD_A(kt);
      #pragma unroll
      for (int ct = 0; ct < 2; ++ct)
        #pragma unroll
        for (int g = 0; g < 4; ++g) {
          const bf16x8 b = *(const bf16x8*)(wl_l + ((kt - 4) * 8 + ct * 4 + g) * 512);
          acc[ct][g] = __builtin_amdgcn_mfma_f32_16x16x32_bf16(afr, b, acc[ct][g], 0, 0, 0);
        }
    }

    // ladder (hand-traced): queue 13 (x+12) -> vmcnt(8) keeps 8+ in flight;
    // every ISSUE strictly follows its buffer's consume; drains to 0.
    bf16x8 af;
    af = LD_A(6);
    CONSUME_S(sA, 0, af, 8); ISSUE_BATCH(sA, 7, 1);
    CONSUME_S(sB, 1, af, 8); ISSUE_BATCH(sB, 8, 0);
    af = LD_A(7);
    CONSUME_S(sC, 0, af, 8); ISSUE_BATCH(sC, 8, 1);
    CONSUME_S(sA, 1, af, 8); ISSUE_BATCH(sA, 9, 0);
    af = LD_A(8);
    CONSUME_S(sB, 0, af, 8); ISSUE_BATCH(sB, 9, 1);
    CONSUME_S(sC, 1, af, 8);
    af = LD_A(9);
    CONSUME_S(sA, 0, af, 4);
    CONSUME_S(sB, 1, af, 0);
    // queue EMPTY: nothing outstanding crosses the barrier.

    // gates + state update (z order: i, j, f, o)
    float h_val[2][4];
    #pragma unroll
    for (int ct = 0; ct < 2; ++ct) {
      #pragma unroll
      for (int q = 0; q < 4; ++q) {
        const float c_old = c_st[ct][q];
        const float ig = sigmoid_f(acc[ct][0][q] + bias_r[ct][0] + wi_r[ct] * c_old);
        const float fg = sigmoid_f(acc[ct][2][q] + bias_r[ct][2] + 1.0f + wf_r[ct] * c_old);
        const float jg = tanh_f(acc[ct][1][q] + bias_r[ct][1]);
        const float c_new = fg * c_old + ig * jg;
        const float og = sigmoid_f(acc[ct][3][q] + bias_r[ct][3] + wo_r[ct] * c_new);
        c_st[ct][q] = c_new;
        h_val[ct][q] = og * tanh_f(c_new);
      }
    }

    __syncthreads();  // all A_lds reads for step t done

    #pragma unroll
    for (int ct = 0; ct < 2; ++ct) {
      const int hc = (w * 2 + ct) * 16 + cl;
      #pragma unroll
      for (int q = 0; q < 4; ++q)
        A_lds[4 * kg + q][64 + hc] = f2bf(h_val[ct][q]);
    }
    if (havex) {
      const int r  = tid >> 5;
      const int f0 = (tid & 31) * 2;
      *(unsigned int*)&A_lds[r][f0] =
          (unsigned int)f2bf(xv.x) | ((unsigned int)f2bf(xv.y) << 16);
    }
    __syncthreads();
  }

  // safety drain before LDS overlay reuse
  asm volatile("s_waitcnt vmcnt(0)" ::: "memory");
  __builtin_amdgcn_sched_barrier(0);
  __syncthreads();

  // ---- epilogue: overlay scratch onto W_lds (all weight reads done) ----
  float* feat  = (float*)W_lds;            // [16][258]
  float* v_l   = feat + BROWS * 258;       // [16][128]
  float* q_l   = v_l + BROWS * 128;        // [16][128]
  float* ispos = q_l + BROWS * 128;        // [16]

  for (int i = tid; i < BROWS * H_DIM; i += 512) {
    const int r = i >> 8, hc = i & 255;
    feat[r * 258 + 2 + hc] = bf2f(A_lds[r][64 + hc]);
  }
  if (tid < BROWS) {
    feat[tid * 258 + 0] = head[(rb + tid) * 3 + 1];
    feat[tid * 258 + 1] = head[(rb + tid) * 3 + 2];
    ispos[tid] = head[(rb + tid) * 3 + 0];
  }
  __syncthreads();

  #pragma unroll
  for (int p = 0; p < 4; ++p) {
    const int idx = p * 512 + tid;
    const int r = idx >> 7, hh = idx & 127;
    float s3 = fc3_b[hh], s4 = fc4_b[hh];
    for (int k = 0; k < 258; ++k) {
      const float fv = feat[r * 258 + k];
      s3 += fv * fc3_w[k * 128 + hh];
      s4 += fv * fc4_w[k * 128 + hh];
    }
    v_l[r * 128 + hh] = fmaxf(s3, 0.0f);
    q_l[r * 128 + hh] = fmaxf(s4, 0.0f);
  }
  __syncthreads();

  if (tid < BROWS) {
    const int r = tid;
    float pa0 = sell_q_b[0], pa1 = sell_q_b[1];
    float ea0 = buy_q_b[0],  ea1 = buy_q_b[1];
    float sv = sell_v_b[0], bv = buy_v_b[0];
    for (int hh = 0; hh < 128; ++hh) {
      const float qv = q_l[r * 128 + hh], vv = v_l[r * 128 + hh];
      pa0 += qv * sell_q_w[hh * 2 + 0];
      pa1 += qv * sell_q_w[hh * 2 + 1];
      ea0 += qv * buy_q_w[hh * 2 + 0];
      ea1 += qv * buy_q_w[hh * 2 + 1];
      sv += vv * sell_v_w[hh];
      bv += vv * buy_v_w[hh];
    }
    const float pm = 0.5f * (pa0 + pa1), em = 0.5f * (ea0 + ea1);
    const float pq0 = pa0 - pm + sv, pq1 = pa1 - pm + sv;
    const float eq0 = ea0 - em + bv, eq1 = ea1 - em + bv;
    const float ip = ispos[r];
    out[(size_t)(rb + r) * 2 + 0] = (ip != 0.0f) ? pq0 : eq0;
    out[(size_t)(rb + r) * 2 + 1] = ((1.0f - ip) != 0.0f) ? pq1 : eq1;
  }
}

extern "C" void kernel_launch(void* const* d_in, const int* in_sizes, int n_in,
                              void* d_out, int out_size, void* d_ws, size_t ws_size,
                              hipStream_t stream) {
  (void)in_sizes; (void)n_in; (void)out_size; (void)ws_size;
  const float* history  = (const float*)d_in[0];
  const float* head     = (const float*)d_in[1];
  const float* Wk       = (const float*)d_in[2];
  const float* bias     = (const float*)d_in[3];
  const float* w_i      = (const float*)d_in[4];
  const float* w_f      = (const float*)d_in[5];
  const float* w_o      = (const float*)d_in[6];
  const float* fc3_w    = (const float*)d_in[7];
  const float* fc3_b    = (const float*)d_in[8];
  const float* fc4_w    = (const float*)d_in[9];
  const float* fc4_b    = (const float*)d_in[10];
  const float* sell_v_w = (const float*)d_in[11];
  const float* sell_v_b = (const float*)d_in[12];
  const float* sell_q_w = (const float*)d_in[13];
  const float* sell_q_b = (const float*)d_in[14];
  const float* buy_v_w  = (const float*)d_in[15];
  const float* buy_v_b  = (const float*)d_in[16];
  const float* buy_q_w  = (const float*)d_in[17];
  const float* buy_q_b  = (const float*)d_in[18];

  unsigned short* Wp = (unsigned short*)d_ws;  // 640 slots * 1 KiB = 640 KiB

  pack_w_kernel<<<NSLOTS, 64, 0, stream>>>(Wk, Wp);
  qlstm_kernel<<<B_TOTAL / BROWS, 512, 0, stream>>>(
      history, head, bias, w_i, w_f, w_o, Wp,
      fc3_w, fc3_b, fc4_w, fc4_b,
      sell_v_w, sell_v_b, sell_q_w, sell_q_b,
      buy_v_w, buy_v_b, buy_q_w, buy_q_b,
      (float*)d_out);
}

// Round 15
// 743.254 us; speedup vs baseline: 2.0917x; 1.0162x over previous
//
#include <hip/hip_runtime.h>
#include <stdint.h>

#define B_TOTAL 1024
#define T_STEPS 128
#define F_DIM   64
#define H_DIM   256
#define BROWS   16
#define APAD    324   // row stride 648B
#define NSLOTS  640   // 8 waves * 80 frags; slot = w*80 + kt*8 + ct*4 + g

typedef float f32x4 __attribute__((ext_vector_type(4)));
typedef short bf16x8 __attribute__((ext_vector_type(8)));

__device__ __forceinline__ unsigned short f2bf(float f) {
  unsigned int u = __float_as_uint(f);
  u += 0x7fffu + ((u >> 16) & 1u);
  return (unsigned short)(u >> 16);
}
__device__ __forceinline__ float bf2f(unsigned short b) {
  return __uint_as_float(((unsigned int)b) << 16);
}
__device__ __forceinline__ float sigmoid_f(float x) {
  return 1.0f / (1.0f + __expf(-x));
}
__device__ __forceinline__ float tanh_f(float x) {
  return 1.0f - 2.0f / (1.0f + __expf(2.0f * x));
}

// Pack kernel weights (320x1024 fp32 row-major) into bf16 MFMA-B fragments,
// wave-major: slot = w*80 + kt*8 + ct*4 + g; ntile = g*16 + w*2 + ct.
__global__ __launch_bounds__(64) void pack_w_kernel(const float* __restrict__ W,
                                                    unsigned short* __restrict__ Wp) {
  const int slot = blockIdx.x;
  const int w  = slot / 80, r = slot % 80;
  const int kt = r >> 3, ct = (r >> 2) & 1, g = r & 3;
  const int ntile = g * 16 + w * 2 + ct;
  const int l   = threadIdx.x;
  const int col = ntile * 16 + (l & 15);
  const int k0  = kt * 32 + (l >> 4) * 8;
  unsigned short* dst = Wp + ((size_t)slot * 64 + l) * 8;
  #pragma unroll
  for (int j = 0; j < 8; ++j)
    dst[j] = f2bf(W[(size_t)(k0 + j) * 1024 + col]);
}

// Opaque pin: un-rematerializable VGPR def -> stays resident (R3/R7-proven
// no-spill class; 3 kt = 96 regs is the max that fits).
#define PIN_V(x) asm volatile("" : "+v"(x))

// Issue 4 streamed fragments of (kt,ct). Wp is shorts; frag slot = 512 shorts.
// Buffers live ONLY within one loop iteration (no loop-carried async regs).
#define ISSUE_BATCH(buf, kt, ct) do {                                        \
    const unsigned short* _p = wp_wl + ((kt) * 8 + (ct) * 4) * 512;          \
    asm volatile("global_load_dwordx4 %0, %4, off\n\t"                       \
                 "global_load_dwordx4 %1, %4, off offset:1024\n\t"           \
                 "global_load_dwordx4 %2, %4, off offset:2048\n\t"           \
                 "global_load_dwordx4 %3, %4, off offset:3072"               \
                 : "=&v"(buf[0]), "=&v"(buf[1]), "=&v"(buf[2]), "=&v"(buf[3])\
                 : "v"(_p));                                                 \
  } while (0)

// Counted wait + sched fences (rule #18), 4 MFMAs into acc[ct].
#define CONSUME_S(buf, ct, afv, N) do {                                      \
    asm volatile("s_waitcnt vmcnt(" #N ")" ::: "memory");                    \
    __builtin_amdgcn_sched_barrier(0);                                       \
    acc[ct][0] = __builtin_amdgcn_mfma_f32_16x16x32_bf16(afv, buf[0], acc[ct][0], 0, 0, 0); \
    acc[ct][1] = __builtin_amdgcn_mfma_f32_16x16x32_bf16(afv, buf[1], acc[ct][1], 0, 0, 0); \
    acc[ct][2] = __builtin_amdgcn_mfma_f32_16x16x32_bf16(afv, buf[2], acc[ct][2], 0, 0, 0); \
    acc[ct][3] = __builtin_amdgcn_mfma_f32_16x16x32_bf16(afv, buf[3], acc[ct][3], 0, 0, 0); \
    __builtin_amdgcn_sched_barrier(0);                                       \
  } while (0)

#define LD_A(buf, kt) (*(const bf16x8*)&(buf)[cl][(kt) * 32 + kg * 8])

__global__ __launch_bounds__(512, 1) void qlstm_kernel(
    const float* __restrict__ history, const float* __restrict__ head,
    const float* __restrict__ bias,
    const float* __restrict__ w_i, const float* __restrict__ w_f, const float* __restrict__ w_o,
    const unsigned short* __restrict__ Wp,
    const float* __restrict__ fc3_w, const float* __restrict__ fc3_b,
    const float* __restrict__ fc4_w, const float* __restrict__ fc4_b,
    const float* __restrict__ sell_v_w, const float* __restrict__ sell_v_b,
    const float* __restrict__ sell_q_w, const float* __restrict__ sell_q_b,
    const float* __restrict__ buy_v_w, const float* __restrict__ buy_v_b,
    const float* __restrict__ buy_q_w, const float* __restrict__ buy_q_b,
    float* __restrict__ out) {

  // Double-buffered A: step t reads A_lds[t&1], writes h/x_{t+1} into
  // A_lds[(t+1)&1] -> ONE barrier per step (write buffer disjoint from all
  // of step t's reads; barrier at step end orders them for step t+1).
  __shared__ unsigned short A_lds[2][BROWS][APAD];
  __shared__ unsigned short W_lds[128 * 512];  // 128 KiB: kt4,5; s = w*16 + (kt-4)*8 + ct*4 + g

  const int tid = threadIdx.x;
  const int w   = tid >> 6;       // wave 0..7
  const int l   = tid & 63;
  const int cl  = l & 15;         // A-row / acc-col
  const int kg  = l >> 4;         // 0..3
  const int rb  = blockIdx.x * BROWS;

  const unsigned short* wp_wl = Wp + (size_t)(w * 80) * 512 + l * 8;
  const unsigned short* wl_l  = W_lds + (w * 16) * 512 + l * 8;

  // ---- preload LDS weight tier: frags f=32..47 (kt4,5) per wave ----
  for (int i = tid; i < 128 * 64; i += 512) {
    const int s = i >> 6, l2 = i & 63;
    const int fsrc = (s >> 4) * 80 + 32 + (s & 15);   // kt in {4,5}
    *(uint4*)&W_lds[((size_t)s * 64 + l2) * 8] =
        *(const uint4*)&Wp[((size_t)fsrc * 64 + l2) * 8];
  }

  // ---- register tier: kt 0..2 (24 frags = 96 regs), VGPR-pinned (R7) ----
  bf16x8 wreg[3][2][4];
  #pragma unroll
  for (int kt = 0; kt < 3; ++kt)
    #pragma unroll
    for (int ct = 0; ct < 2; ++ct)
      #pragma unroll
      for (int g = 0; g < 4; ++g) {
        wreg[kt][ct][g] = *(const bf16x8*)(wp_wl + (kt * 8 + ct * 4 + g) * 512);
        PIN_V(wreg[kt][ct][g]);
      }

  // ---- zero A[0] (h_0 = 0), stage x_0 ----
  for (int i = tid; i < BROWS * APAD; i += 512)
    ((unsigned short*)A_lds[0])[i] = 0;
  __syncthreads();
  {
    const int r  = tid >> 5;
    const int f0 = (tid & 31) * 2;
    const float2 xv0 = *(const float2*)&history[((size_t)(rb + r) * T_STEPS + 0) * F_DIM + f0];
    *(unsigned int*)&A_lds[0][r][f0] =
        (unsigned int)f2bf(xv0.x) | ((unsigned int)f2bf(xv0.y) << 16);
  }

  // ---- per-lane gate constants ----
  float bias_r[2][4], wi_r[2], wf_r[2], wo_r[2];
  #pragma unroll
  for (int ct = 0; ct < 2; ++ct) {
    const int hc = (w * 2 + ct) * 16 + cl;
    wi_r[ct] = w_i[hc]; wf_r[ct] = w_f[hc]; wo_r[ct] = w_o[hc];
    #pragma unroll
    for (int g = 0; g < 4; ++g) bias_r[ct][g] = bias[g * 256 + hc];
  }

  float c_st[2][4];
  #pragma unroll
  for (int ct = 0; ct < 2; ++ct)
    #pragma unroll
    for (int q = 0; q < 4; ++q) c_st[ct][q] = 0.0f;

  __syncthreads();

  // ---- the scan. R7's iteration-local 3-buffer ladder; x-load issued
  //      AFTER the first 3 batches (youngest in queue: in-order vmcnt
  //      retirement no longer serializes L2 batches behind the L3 x-load). ----
  for (int t = 0; t < T_STEPS; ++t) {
    unsigned short (*Acur)[APAD] = A_lds[t & 1];
    unsigned short (*Anxt)[APAD] = A_lds[(t + 1) & 1];

    f32x4 acc[2][4];
    #pragma unroll
    for (int ct = 0; ct < 2; ++ct)
      #pragma unroll
      for (int g = 0; g < 4; ++g)
        acc[ct][g] = (f32x4){0.f, 0.f, 0.f, 0.f};

    // stream tier = kt3 + kt6..9 (10 batches), triple-buffered, in-iteration
    bf16x8 sA[4], sB[4], sC[4];
    ISSUE_BATCH(sA, 3, 0);
    ISSUE_BATCH(sB, 3, 1);
    ISSUE_BATCH(sC, 6, 0);

    // x prefetch for t+1: issued AFTER the batches (queue position 13,
    // youngest). Retired by the 4th consume's vmcnt(8), ~1.5k cy later.
    float2 xv;
    const bool havex = (t + 1 < T_STEPS);
    if (havex) {
      const float* xp =
          &history[((size_t)(rb + (tid >> 5)) * T_STEPS + (t + 1)) * F_DIM + (tid & 31) * 2];
      asm volatile("global_load_dwordx2 %0, %1, off" : "=&v"(xv) : "v"(xp));
    }

    // reg tier kt0..2 (covers L2 latency of the first batches)
    #pragma unroll
    for (int kt = 0; kt < 3; ++kt) {
      const bf16x8 afr = LD_A(Acur, kt);
      #pragma unroll
      for (int ct = 0; ct < 2; ++ct)
        #pragma unroll
        for (int g = 0; g < 4; ++g)
          acc[ct][g] =
              __builtin_amdgcn_mfma_f32_16x16x32_bf16(afr, wreg[kt][ct][g], acc[ct][g], 0, 0, 0);
    }

    // LDS tier kt4..5 (LDS pipe, parallel to the stream)
    #pragma unroll
    for (int kt = 4; kt < 6; ++kt) {
      const bf16x8 afr = LD_A(Acur, kt);
      #pragma unroll
      for (int ct = 0; ct < 2; ++ct)
        #pragma unroll
        for (int g = 0; g < 4; ++g) {
          const bf16x8 b = *(const bf16x8*)(wl_l + ((kt - 4) * 8 + ct * 4 + g) * 512);
          acc[ct][g] = __builtin_amdgcn_mfma_f32_16x16x32_bf16(afr, b, acc[ct][g], 0, 0, 0);
        }
    }

    // ladder (hand-traced, x at queue position 13):
    // waits: 9,9,9,8,8,8,8,8,4,0 — every wait keeps >=8 loads in flight;
    // x retires inside the 4th wait; queue drains to 0 before the barrier.
    bf16x8 af;
    af = LD_A(Acur, 3);
    CONSUME_S(sA, 0, af, 9); ISSUE_BATCH(sA, 6, 1);
    CONSUME_S(sB, 1, af, 9); ISSUE_BATCH(sB, 7, 0);
    af = LD_A(Acur, 6);
    CONSUME_S(sC, 0, af, 9); ISSUE_BATCH(sC, 7, 1);
    CONSUME_S(sA, 1, af, 8); ISSUE_BATCH(sA, 8, 0);
    af = LD_A(Acur, 7);
    CONSUME_S(sB, 0, af, 8); ISSUE_BATCH(sB, 8, 1);
    CONSUME_S(sC, 1, af, 8); ISSUE_BATCH(sC, 9, 0);
    af = LD_A(Acur, 8);
    CONSUME_S(sA, 0, af, 8); ISSUE_BATCH(sA, 9, 1);
    CONSUME_S(sB, 1, af, 8);
    af = LD_A(Acur, 9);
    CONSUME_S(sC, 0, af, 4);
    CONSUME_S(sA, 1, af, 0);
    // queue EMPTY: nothing outstanding crosses the barrier.

    // gates + state update (z order: i, j, f, o)
    float h_val[2][4];
    #pragma unroll
    for (int ct = 0; ct < 2; ++ct) {
      #pragma unroll
      for (int q = 0; q < 4; ++q) {
        const float c_old = c_st[ct][q];
        const float ig = sigmoid_f(acc[ct][0][q] + bias_r[ct][0] + wi_r[ct] * c_old);
        const float fg = sigmoid_f(acc[ct][2][q] + bias_r[ct][2] + 1.0f + wf_r[ct] * c_old);
        const float jg = tanh_f(acc[ct][1][q] + bias_r[ct][1]);
        const float c_new = fg * c_old + ig * jg;
        const float og = sigmoid_f(acc[ct][3][q] + bias_r[ct][3] + wo_r[ct] * c_new);
        c_st[ct][q] = c_new;
        h_val[ct][q] = og * tanh_f(c_new);
      }
    }

    // write h (and x_{t+1}) into the OTHER buffer -> single barrier/step.
    #pragma unroll
    for (int ct = 0; ct < 2; ++ct) {
      const int hc = (w * 2 + ct) * 16 + cl;
      #pragma unroll
      for (int q = 0; q < 4; ++q)
        Anxt[4 * kg + q][64 + hc] = f2bf(h_val[ct][q]);
    }
    if (havex) {
      const int r  = tid >> 5;
      const int f0 = (tid & 31) * 2;
      *(unsigned int*)&Anxt[r][f0] =
          (unsigned int)f2bf(xv.x) | ((unsigned int)f2bf(xv.y) << 16);
    }
    __syncthreads();  // Anxt writes visible before step t+1 reads it
  }

  // final h is in A_lds[0] (T even). Safety drain before LDS overlay reuse.
  asm volatile("s_waitcnt vmcnt(0)" ::: "memory");
  __builtin_amdgcn_sched_barrier(0);
  __syncthreads();

  // ---- epilogue: overlay scratch onto W_lds (all weight reads done) ----
  float* feat  = (float*)W_lds;            // [16][258]
  float* v_l   = feat + BROWS * 258;       // [16][128]
  float* q_l   = v_l + BROWS * 128;        // [16][128]
  float* ispos = q_l + BROWS * 128;        // [16]

  for (int i = tid; i < BROWS * H_DIM; i += 512) {
    const int r = i >> 8, hc = i & 255;
    feat[r * 258 + 2 + hc] = bf2f(A_lds[0][r][64 + hc]);
  }
  if (tid < BROWS) {
    feat[tid * 258 + 0] = head[(rb + tid) * 3 + 1];
    feat[tid * 258 + 1] = head[(rb + tid) * 3 + 2];
    ispos[tid] = head[(rb + tid) * 3 + 0];
  }
  __syncthreads();

  #pragma unroll
  for (int p = 0; p < 4; ++p) {
    const int idx = p * 512 + tid;
    const int r = idx >> 7, hh = idx & 127;
    float s3 = fc3_b[hh], s4 = fc4_b[hh];
    for (int k = 0; k < 258; ++k) {
      const float fv = feat[r * 258 + k];
      s3 += fv * fc3_w[k * 128 + hh];
      s4 += fv * fc4_w[k * 128 + hh];
    }
    v_l[r * 128 + hh] = fmaxf(s3, 0.0f);
    q_l[r * 128 + hh] = fmaxf(s4, 0.0f);
  }
  __syncthreads();

  if (tid < BROWS) {
    const int r = tid;
    float pa0 = sell_q_b[0], pa1 = sell_q_b[1];
    float ea0 = buy_q_b[0],  ea1 = buy_q_b[1];
    float sv = sell_v_b[0], bv = buy_v_b[0];
    for (int hh = 0; hh < 128; ++hh) {
      const float qv = q_l[r * 128 + hh], vv = v_l[r * 128 + hh];
      pa0 += qv * sell_q_w[hh * 2 + 0];
      pa1 += qv * sell_q_w[hh * 2 + 1];
      ea0 += qv * buy_q_w[hh * 2 + 0];
      ea1 += qv * buy_q_w[hh * 2 + 1];
      sv += vv * sell_v_w[hh];
      bv += vv * buy_v_w[hh];
    }
    const float pm = 0.5f * (pa0 + pa1), em = 0.5f * (ea0 + ea1);
    const float pq0 = pa0 - pm + sv, pq1 = pa1 - pm + sv;
    const float eq0 = ea0 - em + bv, eq1 = ea1 - em + bv;
    const float ip = ispos[r];
    out[(size_t)(rb + r) * 2 + 0] = (ip != 0.0f) ? pq0 : eq0;
    out[(size_t)(rb + r) * 2 + 1] = ((1.0f - ip) != 0.0f) ? pq1 : eq1;
  }
}

extern "C" void kernel_launch(void* const* d_in, const int* in_sizes, int n_in,
                              void* d_out, int out_size, void* d_ws, size_t ws_size,
                              hipStream_t stream) {
  (void)in_sizes; (void)n_in; (void)out_size; (void)ws_size;
  const float* history  = (const float*)d_in[0];
  const float* head     = (const float*)d_in[1];
  const float* Wk       = (const float*)d_in[2];
  const float* bias     = (const float*)d_in[3];
  const float* w_i      = (const float*)d_in[4];
  const float* w_f      = (const float*)d_in[5];
  const float* w_o      = (const float*)d_in[6];
  const float* fc3_w    = (const float*)d_in[7];
  const float* fc3_b    = (const float*)d_in[8];
  const float* fc4_w    = (const float*)d_in[9];
  const float* fc4_b    = (const float*)d_in[10];
  const float* sell_v_w = (const float*)d_in[11];
  const float* sell_v_b = (const float*)d_in[12];
  const float* sell_q_w = (const float*)d_in[13];
  const float* sell_q_b = (const float*)d_in[14];
  const float* buy_v_w  = (const float*)d_in[15];
  const float* buy_v_b  = (const float*)d_in[16];
  const float* buy_q_w  = (const float*)d_in[17];
  const float* buy_q_b  = (const float*)d_in[18];

  unsigned short* Wp = (unsigned short*)d_ws;  // 640 slots * 1 KiB = 640 KiB

  pack_w_kernel<<<NSLOTS, 64, 0, stream>>>(Wk, Wp);
  qlstm_kernel<<<B_TOTAL / BROWS, 512, 0, stream>>>(
      history, head, bias, w_i, w_f, w_o, Wp,
      fc3_w, fc3_b, fc4_w, fc4_b,
      sell_v_w, sell_v_b, sell_q_w, sell_q_b,
      buy_v_w, buy_v_b, buy_q_w, buy_q_b,
      (float*)d_out);
}